// Round 3
// baseline (5388.644 us; speedup 1.0000x reference)
//
#include <hip/hip_runtime.h>

#define DIM 64
#define TWO_DIM 128

__device__ __forceinline__ float fast_tanh(float x) {
  float cx = fminf(fmaxf(x, -15.0f), 15.0f);
  float e = __expf(2.0f * cx);
  return (e - 1.0f) / (e + 1.0f);
}

// histogram: cnt[idx[i]] += 1
__global__ void k_hist(const int* __restrict__ idx, int* __restrict__ cnt, int n) {
  int i = blockIdx.x * blockDim.x + threadIdx.x;
  if (i < n) atomicAdd(&cnt[idx[i]], 1);
}

// single-block exclusive scan of deg[0..n) -> offs, cursor (copy)
__global__ void k_scan(const int* __restrict__ deg, int* __restrict__ offs,
                       int* __restrict__ cursor, int n, int chunk) {
  __shared__ int part[1024];
  int t = threadIdx.x;
  int lo = t * chunk, hi = min(lo + chunk, n);
  int s = 0;
  for (int i = lo; i < hi; ++i) s += deg[i];
  part[t] = s;
  __syncthreads();
  for (int off = 1; off < 1024; off <<= 1) {
    int v = (t >= off) ? part[t - off] : 0;
    __syncthreads();
    part[t] += v;
    __syncthreads();
  }
  int run = part[t] - s;  // exclusive prefix of this thread's chunk
  for (int i = lo; i < hi; ++i) {
    offs[i] = run;
    cursor[i] = run;
    run += deg[i];
  }
}

__global__ void k_scatter(const int* __restrict__ src, const int* __restrict__ dst,
                          int* __restrict__ cursor, int* __restrict__ csr, int E) {
  int e = blockIdx.x * blockDim.x + threadIdx.x;
  if (e < E) {
    int p = atomicAdd(&cursor[dst[e]], 1);
    csr[p] = src[e];
  }
}

// one 64-lane wave per node; lane = feature. agg[n][t] = sum over in-edges x[src][t]
__global__ void k_gather(const float* __restrict__ x, const int* __restrict__ csr,
                         const int* __restrict__ offs, const int* __restrict__ deg,
                         float* __restrict__ agg, int n) {
  int node = blockIdx.x * 4 + (threadIdx.x >> 6);
  int t = threadIdx.x & 63;
  if (node >= n) return;
  int s = offs[node], d = deg[node];
  float acc = 0.0f;
  for (int base = 0; base < d; base += 64) {
    int m = min(64, d - base);
    int myi = (t < m) ? csr[s + base + t] : 0;
    for (int i = 0; i < m; ++i) {
      int sn = __shfl(myi, i);
      acc += x[(size_t)sn * DIM + t];
    }
  }
  agg[(size_t)node * DIM + t] = acc;
}

// fold BN(eval) into scale/shift
__global__ void k_prep(const float* __restrict__ b1, const float* __restrict__ gamma,
                       const float* __restrict__ beta, float* __restrict__ sc,
                       float* __restrict__ sh) {
  int i = threadIdx.x;
  if (i < TWO_DIM) {
    float s = gamma[i] * rsqrtf(1.0f + 1e-5f);
    sc[i] = s;
    sh[i] = b1[i] * s + beta[i];
  }
}

// Wave-per-node MLP, lane = feature. NO per-thread arrays (spill-proof).
// W1 kept in original [DIM][TWO_DIM] layout:  sW1[k*128 + j]   (lane=j)
// W2 kept in original [TWO_DIM][DIM] layout:  sW2[j*64 + i]    (lane=i)
// Each wave processes 2 nodes per iteration (weight reads shared).
// POOL: atomically accumulate tanh output into pooled[batch[node]].
template <bool POOL>
__global__ void k_mlp(const float* __restrict__ xin, const float* __restrict__ agg,
                      const float* __restrict__ epsp,
                      const float* __restrict__ W1, const float* __restrict__ sc,
                      const float* __restrict__ sh, const float* __restrict__ W2,
                      const float* __restrict__ b2, float* __restrict__ hout,
                      float* __restrict__ pooled, const int* __restrict__ batch,
                      int n) {
  __shared__ float sW1[DIM * TWO_DIM];   // 32 KB
  __shared__ float sW2[TWO_DIM * DIM];   // 32 KB
  __shared__ float ssc[TWO_DIM], ssh[TWO_DIM], sb2[DIM];

  int t = threadIdx.x;
  // stage weights (float4; 4096 float4 / 512 threads = 8 each)
  const float4* gW1 = reinterpret_cast<const float4*>(W1);
  const float4* gW2 = reinterpret_cast<const float4*>(W2);
  float4* lW1 = reinterpret_cast<float4*>(sW1);
  float4* lW2 = reinterpret_cast<float4*>(sW2);
#pragma unroll
  for (int q = 0; q < 4; ++q) {
    lW1[q * 512 + t] = gW1[q * 512 + t];
    lW2[q * 512 + t] = gW2[q * 512 + t];
  }
  if (t < TWO_DIM) {
    ssc[t] = sc[t];
    ssh[t] = sh[t];
  }
  if (t < DIM) sb2[t] = b2[t];
  __syncthreads();

  const int lane = t & 63;
  const int gwave = blockIdx.x * (blockDim.x >> 6) + (t >> 6);
  const int nwaves = gridDim.x * (blockDim.x >> 6);
  const float ep = 1.0f + epsp[0];
  const float sc_a = ssc[lane], sc_b = ssc[lane + 64];
  const float sh_a = ssh[lane], sh_b = ssh[lane + 64];
  const float b2l = sb2[lane];

  for (int n0 = gwave * 2; n0 < n; n0 += nwaves * 2) {
    const int n1 = n0 + 1;
    const bool has1 = n1 < n;
    float v0 = ep * xin[(size_t)n0 * DIM + lane] + agg[(size_t)n0 * DIM + lane];
    float v1 = has1
                   ? ep * xin[(size_t)n1 * DIM + lane] + agg[(size_t)n1 * DIM + lane]
                   : 0.0f;

    // layer 1: lane j accumulates hidden units j and j+64 for both nodes
    float a00 = 0.0f, a10 = 0.0f, a01 = 0.0f, a11 = 0.0f;
#pragma unroll
    for (int k = 0; k < DIM; ++k) {
      float wa = sW1[k * TWO_DIM + lane];
      float wb = sW1[k * TWO_DIM + 64 + lane];
      float s0 = __shfl(v0, k);
      float s1 = __shfl(v1, k);
      a00 += s0 * wa;
      a10 += s0 * wb;
      a01 += s1 * wa;
      a11 += s1 * wb;
    }
    // BN + tanh
    float t00 = fast_tanh(a00 * sc_a + sh_a);
    float t10 = fast_tanh(a10 * sc_b + sh_b);
    float t01 = fast_tanh(a01 * sc_a + sh_a);
    float t11 = fast_tanh(a11 * sc_b + sh_b);

    // layer 2: lane i accumulates output unit i for both nodes
    float z0 = 0.0f, z1 = 0.0f;
#pragma unroll
    for (int j = 0; j < DIM; ++j) {
      float wa = sW2[j * DIM + lane];
      float wb = sW2[(j + 64) * DIM + lane];
      float p0 = __shfl(t00, j);
      float q0 = __shfl(t10, j);
      z0 += p0 * wa + q0 * wb;
      float p1 = __shfl(t01, j);
      float q1 = __shfl(t11, j);
      z1 += p1 * wa + q1 * wb;
    }

    if (POOL) {
      float o0 = fast_tanh(z0 + b2l);
      int b0 = batch[n0];
      atomicAdd(&pooled[(size_t)b0 * DIM + lane], o0);
      if (has1) {
        float o1 = fast_tanh(z1 + b2l);
        int b1i = batch[n1];
        atomicAdd(&pooled[(size_t)b1i * DIM + lane], o1);
      }
    } else {
      hout[(size_t)n0 * DIM + lane] = fast_tanh(z0 + b2l);
      if (has1) hout[(size_t)n1 * DIM + lane] = fast_tanh(z1 + b2l);
    }
  }
}

// out[g][i] = tanh( (pooled[g]/max(cnt,1)) . linW[:,i] + linb[i] )
__global__ void k_out(const float* __restrict__ pooled, const int* __restrict__ cnt,
                      const float* __restrict__ linW, const float* __restrict__ linb,
                      float* __restrict__ out) {
  int g = blockIdx.x;
  int i = threadIdx.x;
  int c = cnt[g];
  float inv = 1.0f / (float)(c > 0 ? c : 1);
  float acc = 0.0f;
#pragma unroll
  for (int k = 0; k < DIM; ++k)
    acc += pooled[(size_t)g * DIM + k] * linW[k * DIM + i];
  out[(size_t)g * DIM + i] = fast_tanh(acc * inv + linb[i]);
}

extern "C" void kernel_launch(void* const* d_in, const int* in_sizes, int n_in,
                              void* d_out, int out_size, void* d_ws, size_t ws_size,
                              hipStream_t stream) {
  const float* x = (const float*)d_in[0];
  const int* ei = (const int*)d_in[1];
  const int* batch = (const int*)d_in[2];
  const float* eps1 = (const float*)d_in[3];
  const float* W11 = (const float*)d_in[4];
  const float* b11 = (const float*)d_in[5];
  const float* g1 = (const float*)d_in[6];
  const float* be1 = (const float*)d_in[7];
  const float* W12 = (const float*)d_in[8];
  const float* b12 = (const float*)d_in[9];
  const float* eps2 = (const float*)d_in[10];
  const float* W21 = (const float*)d_in[11];
  const float* b21 = (const float*)d_in[12];
  const float* g2 = (const float*)d_in[13];
  const float* be2 = (const float*)d_in[14];
  const float* W22 = (const float*)d_in[15];
  const float* b22 = (const float*)d_in[16];
  const float* linW = (const float*)d_in[17];
  const float* linb = (const float*)d_in[18];

  const int n = in_sizes[0] / DIM;       // 100000
  const int E = in_sizes[1] / 2;         // 1600000
  const int G = out_size / DIM;          // 256
  const int* src = ei;
  const int* dst = ei + E;

  size_t off = 0;
  auto alloc = [&](size_t bytes) -> void* {
    void* p = (char*)d_ws + off;
    off += (bytes + 255) & ~(size_t)255;
    return p;
  };
  float* agg = (float*)alloc((size_t)n * DIM * 4);
  float* h1 = (float*)alloc((size_t)n * DIM * 4);
  int* deg = (int*)alloc((size_t)n * 4);
  int* offs = (int*)alloc((size_t)n * 4);
  int* cursor = (int*)alloc((size_t)n * 4);
  int* csr = (int*)alloc((size_t)E * 4);
  float* sc1 = (float*)alloc(TWO_DIM * 4);
  float* sh1 = (float*)alloc(TWO_DIM * 4);
  float* sc2 = (float*)alloc(TWO_DIM * 4);
  float* sh2 = (float*)alloc(TWO_DIM * 4);
  float* pooled = (float*)alloc((size_t)G * DIM * 4);
  int* cnt = (int*)alloc((size_t)G * 4);

  hipMemsetAsync(deg, 0, (size_t)n * 4, stream);
  hipMemsetAsync(cnt, 0, (size_t)G * 4, stream);
  hipMemsetAsync(pooled, 0, (size_t)G * DIM * 4, stream);

  k_hist<<<(E + 255) / 256, 256, 0, stream>>>(dst, deg, E);
  k_hist<<<(n + 255) / 256, 256, 0, stream>>>(batch, cnt, n);
  k_scan<<<1, 1024, 0, stream>>>(deg, offs, cursor, n, (n + 1023) / 1024);
  k_scatter<<<(E + 255) / 256, 256, 0, stream>>>(src, dst, cursor, csr, E);
  k_prep<<<1, TWO_DIM, 0, stream>>>(b11, g1, be1, sc1, sh1);
  k_prep<<<1, TWO_DIM, 0, stream>>>(b21, g2, be2, sc2, sh2);

  k_gather<<<(n + 3) / 4, 256, 0, stream>>>(x, csr, offs, deg, agg, n);
  k_mlp<false><<<1024, 512, 0, stream>>>(x, agg, eps1, W11, sc1, sh1, W12, b12, h1,
                                         nullptr, nullptr, n);
  k_gather<<<(n + 3) / 4, 256, 0, stream>>>(h1, csr, offs, deg, agg, n);
  k_mlp<true><<<1024, 512, 0, stream>>>(h1, agg, eps2, W21, sc2, sh2, W22, b22,
                                        nullptr, pooled, batch, n);
  k_out<<<G, DIM, 0, stream>>>(pooled, cnt, linW, linb, (float*)d_out);
}

// Round 4
// 1046.504 us; speedup vs baseline: 5.1492x; 5.1492x over previous
//
#include <hip/hip_runtime.h>

#define DIM 64
#define TWO_DIM 128

__device__ __forceinline__ float fast_tanh(float x) {
  float cx = fminf(fmaxf(x, -15.0f), 15.0f);
  float e = __expf(2.0f * cx);
  return (e - 1.0f) / (e + 1.0f);
}

// histogram: cnt[idx[i]] += 1
__global__ void k_hist(const int* __restrict__ idx, int* __restrict__ cnt, int n) {
  int i = blockIdx.x * blockDim.x + threadIdx.x;
  if (i < n) atomicAdd(&cnt[idx[i]], 1);
}

// single-block exclusive scan of deg[0..n) -> offs, cursor (copy)
__global__ void k_scan(const int* __restrict__ deg, int* __restrict__ offs,
                       int* __restrict__ cursor, int n, int chunk) {
  __shared__ int part[1024];
  int t = threadIdx.x;
  int lo = t * chunk, hi = min(lo + chunk, n);
  int s = 0;
  for (int i = lo; i < hi; ++i) s += deg[i];
  part[t] = s;
  __syncthreads();
  for (int off = 1; off < 1024; off <<= 1) {
    int v = (t >= off) ? part[t - off] : 0;
    __syncthreads();
    part[t] += v;
    __syncthreads();
  }
  int run = part[t] - s;  // exclusive prefix of this thread's chunk
  for (int i = lo; i < hi; ++i) {
    offs[i] = run;
    cursor[i] = run;
    run += deg[i];
  }
}

__global__ void k_scatter(const int* __restrict__ src, const int* __restrict__ dst,
                          int* __restrict__ cursor, int* __restrict__ csr, int E) {
  int e = blockIdx.x * blockDim.x + threadIdx.x;
  if (e < E) {
    int p = atomicAdd(&cursor[dst[e]], 1);
    csr[p] = src[e];
  }
}

// one 64-lane wave per node; lane = feature. agg[n][t] = sum over in-edges x[src][t]
__global__ void k_gather(const float* __restrict__ x, const int* __restrict__ csr,
                         const int* __restrict__ offs, const int* __restrict__ deg,
                         float* __restrict__ agg, int n) {
  int node = blockIdx.x * 4 + (threadIdx.x >> 6);
  int t = threadIdx.x & 63;
  if (node >= n) return;
  int s = offs[node], d = deg[node];
  float acc = 0.0f;
  for (int base = 0; base < d; base += 64) {
    int m = min(64, d - base);
    int myi = (t < m) ? csr[s + base + t] : 0;
    for (int i = 0; i < m; ++i) {
      int sn = __shfl(myi, i);
      acc += x[(size_t)sn * DIM + t];
    }
  }
  agg[(size_t)node * DIM + t] = acc;
}

// fold BN(eval) into scale/shift
__global__ void k_prep(const float* __restrict__ b1, const float* __restrict__ gamma,
                       const float* __restrict__ beta, float* __restrict__ sc,
                       float* __restrict__ sh) {
  int i = threadIdx.x;
  if (i < TWO_DIM) {
    float s = gamma[i] * rsqrtf(1.0f + 1e-5f);
    sc[i] = s;
    sh[i] = b1[i] * s + beta[i];
  }
}

// Fused GIN MLP: one block = 64 nodes, 512 threads (8 waves).
// lane = node m; wave ty owns j-slice [16ty,16ty+16) (L1) / i-slice [8ty,8ty+8) (L2).
// V and H transposed in LDS -> lane-consecutive conflict-free b32 reads.
// W reads at wave-uniform addresses (scalar/broadcast path, off the LDS pipe).
template <bool POOL>
__launch_bounds__(512, 4)
__global__ void k_mlp(const float* __restrict__ xin, const float* __restrict__ agg,
                      const float* __restrict__ epsp,
                      const float* __restrict__ W1, const float* __restrict__ sc,
                      const float* __restrict__ sh, const float* __restrict__ W2,
                      const float* __restrict__ b2, float* __restrict__ hout,
                      float* __restrict__ pooled, const int* __restrict__ batch,
                      int n) {
  __shared__ float sVT[DIM * DIM];      // [k][m] 16 KB
  __shared__ float sHT[TWO_DIM * DIM];  // [j][m] 32 KB

  const int t = threadIdx.x;
  const int n0 = blockIdx.x * DIM;
  const int valid = min(DIM, n - n0);
  const float ep = 1.0f + epsp[0];

  // phase 0: V = ep*x + agg, transposed into sVT[k][m]
  {
    const float4* x4 = reinterpret_cast<const float4*>(xin + (size_t)n0 * DIM);
    const float4* a4 = reinterpret_cast<const float4*>(agg + (size_t)n0 * DIM);
#pragma unroll
    for (int r = 0; r < 2; ++r) {
      int idx = r * 512 + t;  // float4 index within 64x64 tile
      int m = idx >> 4, k4 = idx & 15;
      float4 xv = make_float4(0.f, 0.f, 0.f, 0.f);
      float4 av = make_float4(0.f, 0.f, 0.f, 0.f);
      if (m < valid) {
        xv = x4[idx];
        av = a4[idx];
      }
      sVT[(4 * k4 + 0) * DIM + m] = ep * xv.x + av.x;
      sVT[(4 * k4 + 1) * DIM + m] = ep * xv.y + av.y;
      sVT[(4 * k4 + 2) * DIM + m] = ep * xv.z + av.z;
      sVT[(4 * k4 + 3) * DIM + m] = ep * xv.w + av.w;
    }
  }
  __syncthreads();

  const int lane = t & 63;  // node index within tile
  const int ty = __builtin_amdgcn_readfirstlane(t >> 6);  // wave id, uniform

  // ---- layer 1: acc[c] = sum_k V[m][k] * W1[k][16ty+c]
  float acc[16];
#pragma unroll
  for (int c = 0; c < 16; ++c) acc[c] = 0.0f;
  {
    const float* __restrict__ vcol = sVT + lane;
    const float* __restrict__ w1s = W1 + 16 * ty;
#pragma unroll 4
    for (int k = 0; k < DIM; ++k) {
      float vk = vcol[k * DIM];
      const float* wr = w1s + k * TWO_DIM;
      float4 w0 = *reinterpret_cast<const float4*>(wr + 0);
      float4 w1v = *reinterpret_cast<const float4*>(wr + 4);
      float4 w2v = *reinterpret_cast<const float4*>(wr + 8);
      float4 w3v = *reinterpret_cast<const float4*>(wr + 12);
      acc[0] += vk * w0.x;  acc[1] += vk * w0.y;
      acc[2] += vk * w0.z;  acc[3] += vk * w0.w;
      acc[4] += vk * w1v.x; acc[5] += vk * w1v.y;
      acc[6] += vk * w1v.z; acc[7] += vk * w1v.w;
      acc[8] += vk * w2v.x; acc[9] += vk * w2v.y;
      acc[10] += vk * w2v.z; acc[11] += vk * w2v.w;
      acc[12] += vk * w3v.x; acc[13] += vk * w3v.y;
      acc[14] += vk * w3v.z; acc[15] += vk * w3v.w;
    }
  }
  // BN + tanh, write sHT[j][m]
  {
    const float4* scs = reinterpret_cast<const float4*>(sc + 16 * ty);
    const float4* shs = reinterpret_cast<const float4*>(sh + 16 * ty);
#pragma unroll
    for (int q = 0; q < 4; ++q) {
      float4 s4 = scs[q];
      float4 h4 = shs[q];
      sHT[(16 * ty + 4 * q + 0) * DIM + lane] = fast_tanh(acc[4 * q + 0] * s4.x + h4.x);
      sHT[(16 * ty + 4 * q + 1) * DIM + lane] = fast_tanh(acc[4 * q + 1] * s4.y + h4.y);
      sHT[(16 * ty + 4 * q + 2) * DIM + lane] = fast_tanh(acc[4 * q + 2] * s4.z + h4.z);
      sHT[(16 * ty + 4 * q + 3) * DIM + lane] = fast_tanh(acc[4 * q + 3] * s4.w + h4.w);
    }
  }
  __syncthreads();

  // ---- layer 2: z[c] = sum_j H[m][j] * W2[j][8ty+c]
  float z[8];
#pragma unroll
  for (int c = 0; c < 8; ++c) z[c] = 0.0f;
  {
    const float* __restrict__ hcol = sHT + lane;
    const float* __restrict__ w2s = W2 + 8 * ty;
#pragma unroll 4
    for (int j = 0; j < TWO_DIM; ++j) {
      float hj = hcol[j * DIM];
      const float* wr = w2s + j * DIM;
      float4 wa = *reinterpret_cast<const float4*>(wr + 0);
      float4 wb = *reinterpret_cast<const float4*>(wr + 4);
      z[0] += hj * wa.x; z[1] += hj * wa.y;
      z[2] += hj * wa.z; z[3] += hj * wa.w;
      z[4] += hj * wb.x; z[5] += hj * wb.y;
      z[6] += hj * wb.z; z[7] += hj * wb.w;
    }
  }

  const int i0 = 8 * ty;
  const float4* b2s = reinterpret_cast<const float4*>(b2 + i0);
  float4 ba = b2s[0], bb = b2s[1];

  if (POOL) {
    int b = batch[min(n0 + lane, n - 1)];
    float o[8];
    o[0] = fast_tanh(z[0] + ba.x); o[1] = fast_tanh(z[1] + ba.y);
    o[2] = fast_tanh(z[2] + ba.z); o[3] = fast_tanh(z[3] + ba.w);
    o[4] = fast_tanh(z[4] + bb.x); o[5] = fast_tanh(z[5] + bb.y);
    o[6] = fast_tanh(z[6] + bb.z); o[7] = fast_tanh(z[7] + bb.w);
    if (lane >= valid) {
#pragma unroll
      for (int c = 0; c < 8; ++c) o[c] = 0.0f;
    }
    bool uni = (__shfl(b, 0) == __shfl(b, 63));
    if (uni) {
#pragma unroll
      for (int c = 0; c < 8; ++c) {
        float s = o[c];
#pragma unroll
        for (int off = 32; off >= 1; off >>= 1) s += __shfl_xor(s, off);
        if (lane == 0) atomicAdd(&pooled[(size_t)b * DIM + i0 + c], s);
      }
    } else if (lane < valid) {
#pragma unroll
      for (int c = 0; c < 8; ++c)
        atomicAdd(&pooled[(size_t)b * DIM + i0 + c], o[c]);
    }
  } else {
    if (lane < valid) {
      float4 oa, ob;
      oa.x = fast_tanh(z[0] + ba.x); oa.y = fast_tanh(z[1] + ba.y);
      oa.z = fast_tanh(z[2] + ba.z); oa.w = fast_tanh(z[3] + ba.w);
      ob.x = fast_tanh(z[4] + bb.x); ob.y = fast_tanh(z[5] + bb.y);
      ob.z = fast_tanh(z[6] + bb.z); ob.w = fast_tanh(z[7] + bb.w);
      float4* hp = reinterpret_cast<float4*>(hout + (size_t)(n0 + lane) * DIM + i0);
      hp[0] = oa;
      hp[1] = ob;
    }
  }
}

// out[g][i] = tanh( (pooled[g]/max(cnt,1)) . linW[:,i] + linb[i] )
__global__ void k_out(const float* __restrict__ pooled, const int* __restrict__ cnt,
                      const float* __restrict__ linW, const float* __restrict__ linb,
                      float* __restrict__ out) {
  int g = blockIdx.x;
  int i = threadIdx.x;
  int c = cnt[g];
  float inv = 1.0f / (float)(c > 0 ? c : 1);
  float acc = 0.0f;
#pragma unroll
  for (int k = 0; k < DIM; ++k)
    acc += pooled[(size_t)g * DIM + k] * linW[k * DIM + i];
  out[(size_t)g * DIM + i] = fast_tanh(acc * inv + linb[i]);
}

extern "C" void kernel_launch(void* const* d_in, const int* in_sizes, int n_in,
                              void* d_out, int out_size, void* d_ws, size_t ws_size,
                              hipStream_t stream) {
  const float* x = (const float*)d_in[0];
  const int* ei = (const int*)d_in[1];
  const int* batch = (const int*)d_in[2];
  const float* eps1 = (const float*)d_in[3];
  const float* W11 = (const float*)d_in[4];
  const float* b11 = (const float*)d_in[5];
  const float* g1 = (const float*)d_in[6];
  const float* be1 = (const float*)d_in[7];
  const float* W12 = (const float*)d_in[8];
  const float* b12 = (const float*)d_in[9];
  const float* eps2 = (const float*)d_in[10];
  const float* W21 = (const float*)d_in[11];
  const float* b21 = (const float*)d_in[12];
  const float* g2 = (const float*)d_in[13];
  const float* be2 = (const float*)d_in[14];
  const float* W22 = (const float*)d_in[15];
  const float* b22 = (const float*)d_in[16];
  const float* linW = (const float*)d_in[17];
  const float* linb = (const float*)d_in[18];

  const int n = in_sizes[0] / DIM;  // 100000
  const int E = in_sizes[1] / 2;    // 1600000
  const int G = out_size / DIM;     // 256
  const int* src = ei;
  const int* dst = ei + E;

  size_t off = 0;
  auto alloc = [&](size_t bytes) -> void* {
    void* p = (char*)d_ws + off;
    off += (bytes + 255) & ~(size_t)255;
    return p;
  };
  float* agg = (float*)alloc((size_t)n * DIM * 4);
  float* h1 = (float*)alloc((size_t)n * DIM * 4);
  int* deg = (int*)alloc((size_t)n * 4);
  int* offs = (int*)alloc((size_t)n * 4);
  int* cursor = (int*)alloc((size_t)n * 4);
  int* csr = (int*)alloc((size_t)E * 4);
  float* sc1 = (float*)alloc(TWO_DIM * 4);
  float* sh1 = (float*)alloc(TWO_DIM * 4);
  float* sc2 = (float*)alloc(TWO_DIM * 4);
  float* sh2 = (float*)alloc(TWO_DIM * 4);
  float* pooled = (float*)alloc((size_t)G * DIM * 4);
  int* cnt = (int*)alloc((size_t)G * 4);

  hipMemsetAsync(deg, 0, (size_t)n * 4, stream);
  hipMemsetAsync(cnt, 0, (size_t)G * 4, stream);
  hipMemsetAsync(pooled, 0, (size_t)G * DIM * 4, stream);

  k_hist<<<(E + 255) / 256, 256, 0, stream>>>(dst, deg, E);
  k_hist<<<(n + 255) / 256, 256, 0, stream>>>(batch, cnt, n);
  k_scan<<<1, 1024, 0, stream>>>(deg, offs, cursor, n, (n + 1023) / 1024);
  k_scatter<<<(E + 255) / 256, 256, 0, stream>>>(src, dst, cursor, csr, E);
  k_prep<<<1, TWO_DIM, 0, stream>>>(b11, g1, be1, sc1, sh1);
  k_prep<<<1, TWO_DIM, 0, stream>>>(b21, g2, be2, sc2, sh2);

  const int nb = (n + DIM - 1) / DIM;
  k_gather<<<(n + 3) / 4, 256, 0, stream>>>(x, csr, offs, deg, agg, n);
  k_mlp<false><<<nb, 512, 0, stream>>>(x, agg, eps1, W11, sc1, sh1, W12, b12, h1,
                                       nullptr, nullptr, n);
  k_gather<<<(n + 3) / 4, 256, 0, stream>>>(h1, csr, offs, deg, agg, n);
  k_mlp<true><<<nb, 512, 0, stream>>>(h1, agg, eps2, W21, sc2, sh2, W22, b22,
                                      nullptr, pooled, batch, n);
  k_out<<<G, DIM, 0, stream>>>(pooled, cnt, linW, linb, (float*)d_out);
}